// Round 1
// baseline (142.131 us; speedup 1.0000x reference)
//
#include <hip/hip_runtime.h>

#define NQ 6
#define BS 3
#define HID 32
#define SNAPS 16
#define BATCH 1024
#define DIM 64
#define XDIM 24      // NQ + NQ*BS
#define G4 128       // 4*HID

// LDS layout (floats)
#define OFF_WIH  0       // 128 rows x 25 (padded from 24) = 3200
#define OFF_WHH  3200    // 128 rows x 33 (padded from 32) = 4224
#define OFF_B    7424    // 128 (b_ih + b_hh combined)
#define OFF_WP   7552    // 6 x 97 (padded from 96) = 582
#define OFF_BP   8134    // 18
// recon overlay (reuses weight region [0, 8152)):
#define OFF_KA   0       // 16 feats x 64 x 2 = 2048
#define OFF_KB   2048    // 2048
// persistent region:
#define OFF_FEAT 8152    // 16 x 24 = 384
#define OFF_X    8536    // 24
#define OFF_H    8560    // 32
#define OFF_C    8592    // 32
#define OFF_G    8624    // 128
#define OFF_P    8752    // 18
#define SMEM_FLOATS 8770

__device__ __forceinline__ void rc_entry(float g, float b0, float b1, float b2,
                                         int i, int j, float& re, float& im) {
    // rc = (I + 3*shadow*B)/2, B = b0*sx + b1*sy + b2*sz ; g = 1.5*shadow
    if (i == j) { re = 0.5f + (i ? -g * b2 : g * b2); im = 0.0f; }
    else        { re = g * b0;  im = (i ? g * b1 : -g * b1); }
}

__global__ __launch_bounds__(256, 4)
void lstm_shadow_kernel(const float* __restrict__ snapshot,   // (B,6)
                        const float* __restrict__ bcv,        // (B,6,3)
                        const float* __restrict__ h0,         // (B,32)
                        const float* __restrict__ c0,         // (B,32)
                        const float* __restrict__ W_ih,       // (128,24)
                        const float* __restrict__ W_hh,       // (128,32)
                        const float* __restrict__ b_ih,       // (128)
                        const float* __restrict__ b_hh,       // (128)
                        const float* __restrict__ Wp,         // (6,32,3)
                        const float* __restrict__ bp,         // (6,3)
                        float* __restrict__ out)              // (B,2,64,64) flat + (B,6,3)
{
    __shared__ float smem[SMEM_FLOATS];
    const int b = blockIdx.x;
    const int t = threadIdx.x;

    float* sWih  = smem + OFF_WIH;
    float* sWhh  = smem + OFF_WHH;
    float* sb    = smem + OFF_B;
    float* sWp   = smem + OFF_WP;
    float* sbp   = smem + OFF_BP;
    float* sfeat = smem + OFF_FEAT;
    float* sx    = smem + OFF_X;
    float* sh    = smem + OFF_H;
    float* sc    = smem + OFF_C;
    float* sg    = smem + OFF_G;
    float* sp    = smem + OFF_P;

    // ---- stage weights into LDS (padded strides to avoid bank conflicts) ----
    for (int idx = t; idx < G4 * XDIM; idx += 256) {
        int r = idx / XDIM, cc = idx - r * XDIM;
        sWih[r * 25 + cc] = W_ih[idx];
    }
    for (int idx = t; idx < G4 * HID; idx += 256) {
        int r = idx >> 5, cc = idx & 31;
        sWhh[r * 33 + cc] = W_hh[idx];
    }
    if (t < G4) sb[t] = b_ih[t] + b_hh[t];
    for (int idx = t; idx < NQ * HID * BS; idx += 256) {
        int q = idx / 96, rest = idx - q * 96;
        sWp[q * 97 + rest] = Wp[idx];
    }
    if (t < NQ * BS) sbp[t] = bp[t];

    // ---- initial state ----
    if (t < HID) { sh[t] = h0[b * HID + t]; sc[t] = c0[b * HID + t]; }
    if (t < XDIM) {
        float v = (t < NQ) ? snapshot[b * NQ + t] : bcv[b * (NQ * BS) + (t - NQ)];
        sx[t] = v; sfeat[t] = v;
    }
    __syncthreads();

    // ---- LSTM chain (15 steps). snaps[q] = sum_s probs[q,s]^2 (M^2 = |p|^2 I). ----
    for (int step = 0; step < SNAPS - 1; ++step) {
        if (t < G4) {
            float g = sb[t];
            const float* wi = &sWih[t * 25];
            #pragma unroll
            for (int k = 0; k < XDIM; ++k) g += sx[k] * wi[k];
            const float* wh = &sWhh[t * 33];
            #pragma unroll
            for (int k = 0; k < HID; ++k) g += sh[k] * wh[k];
            sg[t] = g;
        }
        __syncthreads();
        if (t < HID) {
            float gi = sg[t], gf = sg[32 + t], gg = sg[64 + t], go = sg[96 + t];
            float si = 1.0f / (1.0f + __expf(-gi));
            float sf = 1.0f / (1.0f + __expf(-gf));
            float so = 1.0f / (1.0f + __expf(-go));
            float cn = sf * sc[t] + si * tanhf(gg);
            sc[t] = cn;
            sh[t] = so * tanhf(cn);
        }
        __syncthreads();
        if (t < NQ * BS) {
            int q = t / 3, s = t - q * 3;
            const float* wp = &sWp[q * 97 + s];
            float l = sbp[t];
            #pragma unroll
            for (int h = 0; h < HID; ++h) l += sh[h] * wp[h * 3];
            sp[t] = l;
        }
        __syncthreads();
        if (t < NQ) {
            float l0 = sp[3 * t], l1 = sp[3 * t + 1], l2 = sp[3 * t + 2];
            float m = fmaxf(l0, fmaxf(l1, l2));
            float e0 = __expf(l0 - m), e1 = __expf(l1 - m), e2 = __expf(l2 - m);
            float inv = 1.0f / (e0 + e1 + e2);
            float p0 = e0 * inv, p1 = e1 * inv, p2 = e2 * inv;
            float snap = p0 * p0 + p1 * p1 + p2 * p2;
            float* fx = &sfeat[(step + 1) * XDIM];
            sx[t] = snap;            fx[t] = snap;
            sx[6 + 3 * t]     = p0;  fx[6 + 3 * t]     = p0;
            sx[6 + 3 * t + 1] = p1;  fx[6 + 3 * t + 1] = p1;
            sx[6 + 3 * t + 2] = p2;  fx[6 + 3 * t + 2] = p2;
        }
        __syncthreads();
    }

    // ---- last_bv output (bv part of the last feature = final probs) ----
    if (t < NQ * BS)
        out[(size_t)BATCH * 8192 + (size_t)b * (NQ * BS) + t] = sfeat[15 * XDIM + 6 + t];

    // ---- build K_A = rc0 (x) rc1 (x) rc2 and K_B = rc3 (x) rc4 (x) rc5 per feat ----
    // (overlays weight LDS region; all weight reads completed before last barrier)
    float* sKA = smem + OFF_KA;
    float* sKB = smem + OFF_KB;
    for (int n = t; n < SNAPS * 64; n += 256) {
        int f = n >> 6, a = n & 63;
        const float* fx = &sfeat[f * XDIM];
        int i0 = (a >> 5) & 1, i1 = (a >> 4) & 1, i2 = (a >> 3) & 1;
        int j0 = (a >> 2) & 1, j1 = (a >> 1) & 1, j2 = a & 1;
        // K_A from qubits 0,1,2
        {
            float g0 = 1.5f * fx[0], g1 = 1.5f * fx[1], g2 = 1.5f * fx[2];
            float r0, m0, r1, m1, r2, m2;
            rc_entry(g0, fx[6], fx[7], fx[8],   i0, j0, r0, m0);
            rc_entry(g1, fx[9], fx[10], fx[11], i1, j1, r1, m1);
            rc_entry(g2, fx[12], fx[13], fx[14], i2, j2, r2, m2);
            float pr = r0 * r1 - m0 * m1, pi = r0 * m1 + m0 * r1;
            float qr = pr * r2 - pi * m2, qi = pr * m2 + pi * r2;
            sKA[2 * n]     = qr;
            sKA[2 * n + 1] = qi;
        }
        // K_B from qubits 3,4,5
        {
            float g3 = 1.5f * fx[3], g4 = 1.5f * fx[4], g5 = 1.5f * fx[5];
            float r0, m0, r1, m1, r2, m2;
            rc_entry(g3, fx[15], fx[16], fx[17], i0, j0, r0, m0);
            rc_entry(g4, fx[18], fx[19], fx[20], i1, j1, r1, m1);
            rc_entry(g5, fx[21], fx[22], fx[23], i2, j2, r2, m2);
            float pr = r0 * r1 - m0 * m1, pi = r0 * m1 + m0 * r1;
            float qr = pr * r2 - pi * m2, qi = pr * m2 + pi * r2;
            sKB[2 * n]     = qr;
            sKB[2 * n + 1] = qi;
        }
    }
    __syncthreads();

    // ---- accumulate: acc[I,J] = sum_f K_A[f][iA,jA] * K_B[f][iB,jB] ----
    // idx = e*256 + t ; i = 4e + (t>>6), j = t&63  -> iA = e>>1, iB = (t>>6) + 4*(e&1)
    const int w  = t >> 6;
    const int j  = t & 63;
    const int jA = j >> 3;
    const int jB = j & 7;
    const int beta0 = (w << 3) + jB;
    const int beta1 = ((w + 4) << 3) + jB;

    float accr[16], acci[16];
    #pragma unroll
    for (int e = 0; e < 16; ++e) { accr[e] = 0.0f; acci[e] = 0.0f; }

    #pragma unroll
    for (int f = 0; f < SNAPS; ++f) {
        const float* KAf = &sKA[f * 128];
        const float* KBf = &sKB[f * 128];
        float b0r = KBf[2 * beta0], b0i = KBf[2 * beta0 + 1];
        float b1r = KBf[2 * beta1], b1i = KBf[2 * beta1 + 1];
        #pragma unroll
        for (int m = 0; m < 8; ++m) {
            float ar = KAf[2 * (m * 8 + jA)], ai = KAf[2 * (m * 8 + jA) + 1];
            accr[2 * m]     += ar * b0r - ai * b0i;
            acci[2 * m]     += ar * b0i + ai * b0r;
            accr[2 * m + 1] += ar * b1r - ai * b1i;
            acci[2 * m + 1] += ar * b1i + ai * b1r;
        }
    }

    const float inv16 = 1.0f / 16.0f;
    float* outb = out + (size_t)b * 8192;
    #pragma unroll
    for (int e = 0; e < 16; ++e) {
        int idx = e * 256 + t;
        outb[idx]        = accr[e] * inv16;
        outb[4096 + idx] = acci[e] * inv16;
    }
}

extern "C" void kernel_launch(void* const* d_in, const int* in_sizes, int n_in,
                              void* d_out, int out_size, void* d_ws, size_t ws_size,
                              hipStream_t stream) {
    const float* snapshot = (const float*)d_in[0];
    const float* bcv      = (const float*)d_in[1];
    // d_in[2] = rho — mathematically unused: tr(M rho M^dag) = (sum_s p_s^2) tr(rho), tr(rho)=1
    const float* h0       = (const float*)d_in[3];
    const float* c0       = (const float*)d_in[4];
    const float* W_ih     = (const float*)d_in[5];
    const float* W_hh     = (const float*)d_in[6];
    const float* b_ih     = (const float*)d_in[7];
    const float* b_hh     = (const float*)d_in[8];
    const float* Wp       = (const float*)d_in[9];
    const float* bp       = (const float*)d_in[10];
    // d_in[11], d_in[12] = basis_r, basis_i — constants folded into rc_entry
    float* out = (float*)d_out;

    lstm_shadow_kernel<<<BATCH, 256, 0, stream>>>(
        snapshot, bcv, h0, c0, W_ih, W_hh, b_ih, b_hh, Wp, bp, out);
}

// Round 2
// 136.268 us; speedup vs baseline: 1.0430x; 1.0430x over previous
//
#include <hip/hip_runtime.h>

#define NQ 6
#define BS 3
#define HID 32
#define SNAPS 16
#define BATCH 1024
#define XDIM 24      // NQ + NQ*BS
#define G4 128       // 4*HID

// LDS float offsets (all multiples of 4 for float4 alignment)
#define OFF_KA   0       // 16 f x 160 (8 cols x 20-float padded col: [j][i] complex)
#define OFF_KB   2560    // 16 f x 160
#define OFF_WPT  5120    // 18 rows x 36 (WpT[(3q+s)][h])
#define OFF_BP   5768    // 18 (+2 pad)
#define OFF_FEAT 5788    // 16 x 24
#define OFF_X    6172    // 24
#define OFF_H    6196    // 32
#define OFF_G    6228    // 128
#define SMEM_FLOATS 6356

__device__ __forceinline__ float sigm_f(float x) { return 1.0f / (1.0f + __expf(-x)); }
// tanh(x) = 1 - 2/(exp(2x)+1): exact at +-inf, ~1e-6 rel err, no branches
__device__ __forceinline__ float tanh_f(float x) { return 1.0f - 2.0f / (__expf(2.0f * x) + 1.0f); }

__device__ __forceinline__ void rc_entry(float g, float b0, float b1, float b2,
                                         int i, int j, float& re, float& im) {
    // rc = (I + 3*shadow*B)/2, B = b0*sx + b1*sy + b2*sz ; g = 1.5*shadow
    if (i == j) { re = 0.5f + (i ? -g * b2 : g * b2); im = 0.0f; }
    else        { re = g * b0;  im = (i ? g * b1 : -g * b1); }
}

// Build one entry of K (3-qubit kron), stored TRANSPOSED with pad:
// dst[(col)*20 + 2*row + {0,1}] ; a encodes row=a>>3 (bits i0i1i2), col=a&7
__device__ __forceinline__ void build_K(const float* fx, int half, int a, float* dst) {
    int i0 = (a >> 5) & 1, i1 = (a >> 4) & 1, i2 = (a >> 3) & 1;
    int j0 = (a >> 2) & 1, j1 = (a >> 1) & 1, j2 = a & 1;
    int q = 3 * half;
    float g0 = 1.5f * fx[q], g1 = 1.5f * fx[q + 1], g2 = 1.5f * fx[q + 2];
    const float* bb = fx + 6 + 3 * q;
    float r0, m0, r1, m1, r2, m2;
    rc_entry(g0, bb[0], bb[1], bb[2], i0, j0, r0, m0);
    rc_entry(g1, bb[3], bb[4], bb[5], i1, j1, r1, m1);
    rc_entry(g2, bb[6], bb[7], bb[8], i2, j2, r2, m2);
    float pr = r0 * r1 - m0 * m1, pi = r0 * m1 + m0 * r1;
    float qr = pr * r2 - pi * m2, qi = pr * m2 + pi * r2;
    int idx = (a & 7) * 20 + 2 * (a >> 3);
    dst[idx] = qr; dst[idx + 1] = qi;
}

__global__ __launch_bounds__(256, 4)
void lstm_shadow_kernel(const float* __restrict__ snapshot,   // (B,6)
                        const float* __restrict__ bcv,        // (B,6,3)
                        const float* __restrict__ h0,         // (B,32)
                        const float* __restrict__ c0,         // (B,32)
                        const float* __restrict__ W_ih,       // (128,24)
                        const float* __restrict__ W_hh,       // (128,32)
                        const float* __restrict__ b_ih,       // (128)
                        const float* __restrict__ b_hh,       // (128)
                        const float* __restrict__ Wp,         // (6,32,3)
                        const float* __restrict__ bp,         // (6,3)
                        float* __restrict__ out)              // (B,2,64,64) + (B,6,3)
{
    __shared__ __align__(16) float smem[SMEM_FLOATS];
    const int b = blockIdx.x;
    const int t = threadIdx.x;

    float* sKA   = smem + OFF_KA;
    float* sKB   = smem + OFF_KB;
    float* sWpT  = smem + OFF_WPT;
    float* sbp   = smem + OFF_BP;
    float* sfeat = smem + OFF_FEAT;
    float* sx    = smem + OFF_X;
    float* sh    = smem + OFF_H;
    float* sg    = smem + OFF_G;

    // ---- per-thread register state ----
    float4 wih4[6], whh4[8];          // gate row weights (threads t<128)
    float breg = 0.0f, creg = 0.0f;   // combined bias; LSTM cell state (lanes t<32)

    if (t < G4) {
        const float4* wi = (const float4*)(W_ih + t * 24);   // 96B rows, 16B aligned
        #pragma unroll
        for (int k = 0; k < 6; ++k) wih4[k] = wi[k];
        const float4* wh = (const float4*)(W_hh + t * 32);
        #pragma unroll
        for (int k = 0; k < 8; ++k) whh4[k] = wh[k];
        breg = b_ih[t] + b_hh[t];
    }
    // Wp transposed: WpT[(3q+s)][h]
    for (int idx = t; idx < NQ * HID * BS; idx += 256) {
        int q = idx / 96, r = idx - q * 96;
        int h = r / 3, s = r - h * 3;
        sWpT[(q * 3 + s) * 36 + h] = Wp[idx];
    }
    if (t < 18) sbp[t] = bp[t];
    if (t < 32) { sh[t] = h0[b * HID + t]; creg = c0[b * HID + t]; }
    if (t < 24) {
        float v = (t < 6) ? snapshot[b * NQ + t] : bcv[b * 18 + (t - 6)];
        sx[t] = v; sfeat[t] = v;
    }
    __syncthreads();

    // ---- LSTM chain: 15 steps, 2 barriers/step.
    // snaps[q] = sum_s probs^2 (M^2 = |p|^2 I, tr(rho)=1 -> rho unused).
    // waves 2-3 build KA/KB[f=step] concurrently with gate compute.
    for (int step = 0; step < SNAPS - 1; ++step) {
        if (t < G4) {
            const float4* sx4 = (const float4*)sx;   // broadcast reads
            const float4* sh4 = (const float4*)sh;
            float ga = breg, gb = 0.0f;
            #pragma unroll
            for (int k = 0; k < 6; ++k) {
                float4 xq = sx4[k];
                ga += xq.x * wih4[k].x + xq.y * wih4[k].y;
                gb += xq.z * wih4[k].z + xq.w * wih4[k].w;
            }
            #pragma unroll
            for (int k = 0; k < 8; ++k) {
                float4 hq = sh4[k];
                ga += hq.x * whh4[k].x + hq.y * whh4[k].y;
                gb += hq.z * whh4[k].z + hq.w * whh4[k].w;
            }
            sg[t] = ga + gb;
        } else {
            int u = t - G4;
            const float* fx = &sfeat[step * XDIM];   // ready: written step-1 + barrier
            if (u < 64) build_K(fx, 0, u, &sKA[step * 160]);
            else        build_K(fx, 1, u - 64, &sKB[step * 160]);
        }
        __syncthreads();

        // fused activation + projection + softmax, all inside wave 0 (no barrier)
        if (t < 64) {
            if (t < 32) {
                float gi = sg[t], gf = sg[32 + t], gg = sg[64 + t], go = sg[96 + t];
                creg = sigm_f(gf) * creg + sigm_f(gi) * tanh_f(gg);
                float hnew = sigm_f(go) * tanh_f(creg);
                sh[t] = hnew;                 // in-wave DS ordering: later reads see this
            }
            __builtin_amdgcn_wave_barrier();  // keep compiler from reordering DS ops
            // projection: lanes 0..17 compute logit[3q+s]
            int row = (t < 18) ? t : 17;
            const float4* wr  = (const float4*)&sWpT[row * 36];
            const float4* sh4 = (const float4*)sh;
            float la = (t < 18) ? sbp[row] : 0.0f, lb = 0.0f;
            #pragma unroll
            for (int c2 = 0; c2 < 8; ++c2) {
                float4 hq = sh4[c2], wq = wr[c2];
                la += hq.x * wq.x + hq.y * wq.y;
                lb += hq.z * wq.z + hq.w * wq.w;
            }
            float l = la + lb;
            // softmax: lanes 0..5 gather their 3 logits via shfl
            int q3 = (t < 6) ? 3 * t : 0;
            float l0 = __shfl(l, q3), l1 = __shfl(l, q3 + 1), l2 = __shfl(l, q3 + 2);
            if (t < 6) {
                float m = fmaxf(l0, fmaxf(l1, l2));
                float e0 = __expf(l0 - m), e1 = __expf(l1 - m), e2 = __expf(l2 - m);
                float inv = 1.0f / (e0 + e1 + e2);
                float p0 = e0 * inv, p1 = e1 * inv, p2 = e2 * inv;
                float snap = p0 * p0 + p1 * p1 + p2 * p2;
                float* fx2 = &sfeat[(step + 1) * XDIM];
                sx[t] = snap;              fx2[t] = snap;
                sx[6 + 3 * t]     = p0;    fx2[6 + 3 * t]     = p0;
                sx[6 + 3 * t + 1] = p1;    fx2[6 + 3 * t + 1] = p1;
                sx[6 + 3 * t + 2] = p2;    fx2[6 + 3 * t + 2] = p2;
            }
        }
        __syncthreads();
    }

    // ---- f=15 build + last_bv output ----
    if (t < G4) {
        const float* fx = &sfeat[15 * XDIM];
        if (t < 64) build_K(fx, 0, t, &sKA[15 * 160]);
        else        build_K(fx, 1, t - 64, &sKB[15 * 160]);
    } else if (t < G4 + 18) {
        int u = t - G4;
        out[(size_t)BATCH * 8192 + (size_t)b * 18 + u] = sfeat[15 * XDIM + 6 + u];
    }
    __syncthreads();

    // ---- accumulate: acc[I,J] = sum_f KA[f][iA,jA] * KB[f][iB,jB]
    // i = 4e + w, j = t&63 ; iA = i>>3, iB = i&7, jA = j>>3, jB = j&7
    const int w  = t >> 6;
    const int j  = t & 63;
    const int jA = j >> 3;
    const int jB = j & 7;

    float accr[16], acci[16];
    #pragma unroll
    for (int e = 0; e < 16; ++e) { accr[e] = 0.0f; acci[e] = 0.0f; }

    #pragma unroll
    for (int f = 0; f < SNAPS; ++f) {
        const float* KAT = &sKA[f * 160 + jA * 20];   // 16 consecutive floats = col jA
        const float* KBT = &sKB[f * 160 + jB * 20];
        float4 a0 = ((const float4*)KAT)[0];
        float4 a1 = ((const float4*)KAT)[1];
        float4 a2 = ((const float4*)KAT)[2];
        float4 a3 = ((const float4*)KAT)[3];
        float b0r = KBT[2 * w],     b0i = KBT[2 * w + 1];   // iB = w
        float b1r = KBT[2 * w + 8], b1i = KBT[2 * w + 9];   // iB = w+4
        #define CMAC(m, ar, ai)                              \
            accr[2*(m)]   += (ar)*b0r - (ai)*b0i;            \
            acci[2*(m)]   += (ar)*b0i + (ai)*b0r;            \
            accr[2*(m)+1] += (ar)*b1r - (ai)*b1i;            \
            acci[2*(m)+1] += (ar)*b1i + (ai)*b1r;
        CMAC(0, a0.x, a0.y) CMAC(1, a0.z, a0.w)
        CMAC(2, a1.x, a1.y) CMAC(3, a1.z, a1.w)
        CMAC(4, a2.x, a2.y) CMAC(5, a2.z, a2.w)
        CMAC(6, a3.x, a3.y) CMAC(7, a3.z, a3.w)
        #undef CMAC
    }

    const float inv16 = 1.0f / 16.0f;
    float* outb = out + (size_t)b * 8192;
    #pragma unroll
    for (int e = 0; e < 16; ++e) {
        int idx = e * 256 + t;
        outb[idx]        = accr[e] * inv16;
        outb[4096 + idx] = acci[e] * inv16;
    }
}

extern "C" void kernel_launch(void* const* d_in, const int* in_sizes, int n_in,
                              void* d_out, int out_size, void* d_ws, size_t ws_size,
                              hipStream_t stream) {
    const float* snapshot = (const float*)d_in[0];
    const float* bcv      = (const float*)d_in[1];
    // d_in[2] = rho — unused: tr(M rho M^dag) = (sum_s p_s^2) tr(rho), tr(rho)=1
    const float* h0       = (const float*)d_in[3];
    const float* c0       = (const float*)d_in[4];
    const float* W_ih     = (const float*)d_in[5];
    const float* W_hh     = (const float*)d_in[6];
    const float* b_ih     = (const float*)d_in[7];
    const float* b_hh     = (const float*)d_in[8];
    const float* Wp       = (const float*)d_in[9];
    const float* bp       = (const float*)d_in[10];
    // d_in[11], d_in[12] = basis_r, basis_i — folded into rc_entry
    float* out = (float*)d_out;

    lstm_shadow_kernel<<<BATCH, 256, 0, stream>>>(
        snapshot, bcv, h0, c0, W_ih, W_hh, b_ih, b_hh, Wp, bp, out);
}